// Round 8
// baseline (267.228 us; speedup 1.0000x reference)
//
#include <hip/hip_runtime.h>

#define NODES 100000
#define EDGES 1600000
#define BSH 8
#define NBUCK ((NODES + 255) >> BSH)   // 391
#define CHUNK 4096
#define LMAX 8192
#define MCHUNKS ((NODES + 31) / 32)    // 3125 (3125*32 == 100000, no tail)
#define CONVB 12500                    // blocks for conv part of conv_hist
#define MLP1GRID 512                   // 2 blocks/CU (LDS-limited)
#define MLP2GRID 1024
// IN_F = HID_F = 128, OUT_F = 64

using bf16x8 = __attribute__((ext_vector_type(8))) short;
using f32x4  = __attribute__((ext_vector_type(4))) float;
using f32x2  = __attribute__((ext_vector_type(2))) float;

__device__ __forceinline__ unsigned short f2b(float f) {
    unsigned u = __builtin_bit_cast(unsigned, f);
    unsigned r = (u + 0x7FFFu + ((u >> 16) & 1u)) >> 16;
    return (unsigned short)r;
}

// ---- packed f32 helpers (CDNA VOP3P; dual-pump FP32) ----
__device__ __forceinline__ f32x2 pkadd(f32x2 a, f32x2 b) {
    f32x2 d;
    asm("v_pk_add_f32 %0, %1, %2" : "=v"(d) : "v"(a), "v"(b));
    return d;
}
__device__ __forceinline__ f32x2 pkfma(f32x2 a, f32x2 b, f32x2 c) {
    f32x2 d;
    asm("v_pk_fma_f32 %0, %1, %2, %3" : "=v"(d) : "v"(a), "v"(b), "v"(c));
    return d;
}
__device__ __forceinline__ unsigned cvt2bf(float lo, float hi) {
    unsigned r;
    asm("v_cvt_pk_bf16_f32 %0, %1, %2" : "=v"(r) : "v"(lo), "v"(hi));
    return r;
}

// pinned 16B global load (volatile: cannot be sunk/rematerialized)
__device__ __forceinline__ bf16x8 gl16(const unsigned short* p) {
    bf16x8 r;
    asm volatile("global_load_dwordx4 %0, %1, off" : "=&v"(r) : "v"(p));
    return r;
}

// unpack 8 fp8 (uint2) and accumulate into 4 packed-f32 accumulators
__device__ __forceinline__ void addpk8(f32x2* a, uint2 v) {
    a[0] = pkadd(a[0], __builtin_amdgcn_cvt_pk_f32_fp8((int)v.x, false));
    a[1] = pkadd(a[1], __builtin_amdgcn_cvt_pk_f32_fp8((int)v.x, true));
    a[2] = pkadd(a[2], __builtin_amdgcn_cvt_pk_f32_fp8((int)v.y, false));
    a[3] = pkadd(a[3], __builtin_amdgcn_cvt_pk_f32_fp8((int)v.y, true));
}

// ---------------- fused conversions + coarse histogram ----------------

__global__ __launch_bounds__(256) void conv_hist(
    const float* __restrict__ in, unsigned short* __restrict__ outb,
    unsigned char* __restrict__ outq, int n4,
    const float* __restrict__ W1s, const float* __restrict__ W1n,
    const float* __restrict__ W2s, const float* __restrict__ W2n,
    unsigned short* __restrict__ Wt1s, unsigned short* __restrict__ Wt1n,
    unsigned short* __restrict__ Wt2s, unsigned short* __restrict__ Wt2n,
    const int* __restrict__ dst, int* __restrict__ bucket_cnt) {
    int t = threadIdx.x;
    if (blockIdx.x < CONVB) {
        int i = blockIdx.x * 256 + t;
        if (i < n4) {
            float4 v = reinterpret_cast<const float4*>(in)[i];
            uint2 o;
            o.x = (unsigned)f2b(v.x) | ((unsigned)f2b(v.y) << 16);
            o.y = (unsigned)f2b(v.z) | ((unsigned)f2b(v.w) << 16);
            reinterpret_cast<uint2*>(outb)[i] = o;
            int pk = __builtin_amdgcn_cvt_pk_fp8_f32(v.x, v.y, 0, false);
            pk = __builtin_amdgcn_cvt_pk_fp8_f32(v.z, v.w, pk, true);
            reinterpret_cast<unsigned*>(outq)[i] = (unsigned)pk;
        }
        if (i < 16384) {
            int k = i >> 7, n = i & 127;
            Wt1s[n * 128 + k] = f2b(W1s[i]);
            Wt1n[n * 128 + k] = f2b(W1n[i]);
        }
        if (i < 8192) {
            int k = i >> 6, n = i & 63;
            Wt2s[n * 128 + k] = f2b(W2s[i]);
            Wt2n[n * 128 + k] = f2b(W2n[i]);
        }
        return;
    }
    // ---- bhist part ----
    __shared__ int lcnt[512];
    lcnt[t] = 0; lcnt[t + 256] = 0;
    __syncthreads();
    int base = (blockIdx.x - CONVB) * 16384;
    int n = EDGES - base;
    if (n > 16384) n = 16384;
    const int4* d4 = reinterpret_cast<const int4*>(dst + base);
    for (int i = t; i < (n >> 2); i += 256) {
        int4 d = d4[i];
        atomicAdd(&lcnt[d.x >> BSH], 1);
        atomicAdd(&lcnt[d.y >> BSH], 1);
        atomicAdd(&lcnt[d.z >> BSH], 1);
        atomicAdd(&lcnt[d.w >> BSH], 1);
    }
    for (int i = (n & ~3) + t; i < n; i += 256) atomicAdd(&lcnt[dst[base + i] >> BSH], 1);
    __syncthreads();
    if (lcnt[t]) atomicAdd(&bucket_cnt[t], lcnt[t]);
    if (lcnt[t + 256]) atomicAdd(&bucket_cnt[t + 256], lcnt[t + 256]);
}

__global__ void bscan_kernel(const int* __restrict__ bucket_cnt, int* __restrict__ bucket_off,
                             int* __restrict__ gcursor, int* __restrict__ row_ptr) {
    __shared__ int sh[512];
    int t = threadIdx.x;
    int v = (t < NBUCK) ? bucket_cnt[t] : 0;
    sh[t] = v;
    __syncthreads();
    for (int off = 1; off < 512; off <<= 1) {
        int x = (t >= off) ? sh[t - off] : 0;
        __syncthreads();
        sh[t] += x;
        __syncthreads();
    }
    int excl = sh[t] - v;
    if (t < NBUCK) { bucket_off[t] = excl; gcursor[t] = excl; }
    if (t == NBUCK) bucket_off[t] = EDGES;
    if (t == 0) row_ptr[NODES] = EDGES;
}

// Bin edges by coarse bucket; write packed (dst&255)<<24|src runs.
__global__ __launch_bounds__(256) void binscat_kernel(
    const int* __restrict__ src, const int* __restrict__ dst,
    int* __restrict__ gcursor, unsigned* __restrict__ pairs) {
    __shared__ int cnt[512];
    __shared__ int scn[512];
    __shared__ int gbs[512];
    __shared__ int cur[512];
    __shared__ uint2 stage[CHUNK];
    int t = threadIdx.x;
    int base = blockIdx.x * CHUNK;
    int n = EDGES - base;
    if (n > CHUNK) n = CHUNK;

    cnt[t] = 0; cnt[t + 256] = 0;
    __syncthreads();

    uint2 my[16];
#pragma unroll
    for (int i = 0; i < 16; ++i) {
        int idx = t + i * 256;
        if (idx < n) {
            int d = dst[base + idx];
            int s = src[base + idx];
            my[i] = make_uint2((unsigned)d, (unsigned)s);
            atomicAdd(&cnt[d >> BSH], 1);
        } else {
            my[i] = make_uint2(0xFFFFFFFFu, 0);
        }
    }
    __syncthreads();
    scn[t] = cnt[t]; scn[t + 256] = cnt[t + 256];
    __syncthreads();
    for (int off = 1; off < 512; off <<= 1) {
        int a0 = (t >= off) ? scn[t - off] : 0;
        int a1 = (t + 256 >= off) ? scn[t + 256 - off] : 0;
        __syncthreads();
        scn[t] += a0; scn[t + 256] += a1;
        __syncthreads();
    }
    cur[t] = scn[t] - cnt[t];
    cur[t + 256] = scn[t + 256] - cnt[t + 256];
    __syncthreads();
#pragma unroll
    for (int i = 0; i < 16; ++i) {
        if (my[i].x != 0xFFFFFFFFu) {
            int b = (int)(my[i].x >> BSH);
            int p = atomicAdd(&cur[b], 1);
            stage[p] = my[i];
        }
    }
    for (int b2 = t; b2 < 512; b2 += 256) {
        int c = cnt[b2];
        gbs[b2] = (c > 0 && b2 < NBUCK) ? atomicAdd(&gcursor[b2], c) : 0;
    }
    __syncthreads();
    for (int idx = t; idx < n; idx += 256) {
        uint2 p = stage[idx];
        int b = (int)(p.x >> BSH);
        int excl = scn[b] - cnt[b];
        pairs[gbs[b] + idx - excl] = ((p.x & 255u) << 24) | p.y;
    }
}

__global__ __launch_bounds__(256) void localsort_kernel(
    const unsigned* __restrict__ pairs, const int* __restrict__ bucket_off,
    int* __restrict__ row_ptr, int* __restrict__ src_sorted) {
    __shared__ int cnt[256];
    __shared__ int cur[256];
    __shared__ int stage[LMAX];
    int b = blockIdx.x;
    int t = threadIdx.x;
    int node0 = b << BSH;
    int pbeg = bucket_off[b], pend = bucket_off[b + 1];
    int n = pend - pbeg;
    cnt[t] = 0;
    __syncthreads();
    for (int e = pbeg + t; e < pend; e += 256)
        atomicAdd(&cnt[(int)(pairs[e] >> 24)], 1);
    __syncthreads();
    int v = cnt[t];
    cur[t] = v;
    __syncthreads();
    for (int off = 1; off < 256; off <<= 1) {
        int x = (t >= off) ? cur[t - off] : 0;
        __syncthreads();
        cur[t] += x;
        __syncthreads();
    }
    int excl = cur[t] - v;
    int node = node0 + t;
    if (node < NODES) row_ptr[node] = pbeg + excl;
    cur[t] = excl;
    __syncthreads();
    if (n <= LMAX) {
        for (int e = pbeg + t; e < pend; e += 256) {
            unsigned p = pairs[e];
            int pos = atomicAdd(&cur[(int)(p >> 24)], 1);
            stage[pos] = (int)(p & 0xFFFFFFu);
        }
        __syncthreads();
        for (int i = t; i < n; i += 256) src_sorted[pbeg + i] = stage[i];
    } else {
        for (int e = pbeg + t; e < pend; e += 256) {
            unsigned p = pairs[e];
            int pos = atomicAdd(&cur[(int)(p >> 24)], 1);
            src_sorted[pbeg + pos] = (int)(p & 0xFFFFFFu);
        }
    }
}

// ---------------- Mean aggregation, fp8 gather ----------------

__global__ __launch_bounds__(256) void agg128_fp8(
    const unsigned char* __restrict__ xq, const int* __restrict__ row_ptr,
    const int* __restrict__ srcs, unsigned short* __restrict__ out) {
    int wave = (blockIdx.x * 256 + threadIdx.x) >> 6;
    int lane = threadIdx.x & 63;
    int sl = lane & 15;
    int n = wave * 4 + (lane >> 4);
    if (n >= NODES) return;
    int beg = row_ptr[n], end = row_ptr[n + 1];
    int gb = lane & 48;  // group base lane (g*16)

    f32x2 A0[4], A1[4];
#pragma unroll
    for (int i = 0; i < 4; ++i) { A0[i] = {0.f, 0.f}; A1[i] = {0.f, 0.f}; }

    const unsigned char* xs = xq + sl * 8;
    for (int base = beg; base < end; base += 16) {
        int idx = base + sl;
        int sv = (idx < end) ? srcs[idx] : NODES;  // NODES = zero pad row
        uint2 vv[8], ww[8];
#pragma unroll
        for (int j = 0; j < 8; ++j) {
            int s = __shfl(sv, gb + j, 64);
            vv[j] = *reinterpret_cast<const uint2*>(xs + (size_t)s * 128);
        }
#pragma unroll
        for (int j = 0; j < 8; ++j) {
            int s = __shfl(sv, gb + 8 + j, 64);
            ww[j] = *reinterpret_cast<const uint2*>(xs + (size_t)s * 128);
        }
#pragma unroll
        for (int j = 0; j < 8; ++j) addpk8((j & 1) ? A1 : A0, vv[j]);
#pragma unroll
        for (int j = 0; j < 8; ++j) addpk8((j & 1) ? A0 : A1, ww[j]);
    }

    float inv = 1.0f / fmaxf((float)(end - beg), 1.0f);
    f32x2 iv = {inv, inv};
    f32x2 z = {0.f, 0.f};
    f32x2 r0 = pkfma(pkadd(A0[0], A1[0]), iv, z);
    f32x2 r1 = pkfma(pkadd(A0[1], A1[1]), iv, z);
    f32x2 r2 = pkfma(pkadd(A0[2], A1[2]), iv, z);
    f32x2 r3 = pkfma(pkadd(A0[3], A1[3]), iv, z);
    uint4 o;
    o.x = cvt2bf(r0[0], r0[1]);
    o.y = cvt2bf(r1[0], r1[1]);
    o.z = cvt2bf(r2[0], r2[1]);
    o.w = cvt2bf(r3[0], r3[1]);
    *reinterpret_cast<uint4*>(out + (size_t)n * 128 + sl * 8) = o;
}

__global__ __launch_bounds__(256) void agg64_add8(
    const unsigned char* __restrict__ xq, const int* __restrict__ row_ptr,
    const int* __restrict__ srcs, float* __restrict__ out) {
    int wave = (blockIdx.x * 256 + threadIdx.x) >> 6;
    int lane = threadIdx.x & 63;
    int sl = lane & 7;
    int n = wave * 8 + (lane >> 3);
    if (n >= NODES) return;
    int beg = row_ptr[n], end = row_ptr[n + 1];
    int gb = lane & 56;  // group base lane (g*8)

    f32x2 A0[4], A1[4];
#pragma unroll
    for (int i = 0; i < 4; ++i) { A0[i] = {0.f, 0.f}; A1[i] = {0.f, 0.f}; }

    const unsigned char* xs = xq + sl * 8;
    for (int base = beg; base < end; base += 8) {
        int idx = base + sl;
        int sv = (idx < end) ? srcs[idx] : NODES;  // zero pad row
        uint2 vv[8];
#pragma unroll
        for (int j = 0; j < 8; ++j) {
            int s = __shfl(sv, gb + j, 64);
            vv[j] = *reinterpret_cast<const uint2*>(xs + (size_t)s * 64);
        }
#pragma unroll
        for (int j = 0; j < 8; ++j) addpk8((j & 1) ? A1 : A0, vv[j]);
    }

    float inv = 1.0f / fmaxf((float)(end - beg), 1.0f);
    f32x2 iv = {inv, inv};
    float* op = out + (size_t)n * 64 + sl * 8;
    f32x2 r0 = *reinterpret_cast<f32x2*>(op);
    f32x2 r1 = *reinterpret_cast<f32x2*>(op + 2);
    f32x2 r2 = *reinterpret_cast<f32x2*>(op + 4);
    f32x2 r3 = *reinterpret_cast<f32x2*>(op + 6);
    r0 = pkfma(pkadd(A0[0], A1[0]), iv, r0);
    r1 = pkfma(pkadd(A0[1], A1[1]), iv, r1);
    r2 = pkfma(pkadd(A0[2], A1[2]), iv, r2);
    r3 = pkfma(pkadd(A0[3], A1[3]), iv, r3);
    *reinterpret_cast<f32x2*>(op) = r0;
    *reinterpret_cast<f32x2*>(op + 2) = r1;
    *reinterpret_cast<f32x2*>(op + 4) = r2;
    *reinterpret_cast<f32x2*>(op + 6) = r3;
}

// ---------------- MLP layer 1: W1 in LDS, barrier-free loop ----
// x1 = relu(featb@W1s + agg@W1n + b1) -> global bf16 (row-major).
// One barrier after W1 staging; the chunk loop has NO barriers, so waves
// free-run and TLP hides the A-row latency (the v1-v5 fused kernels were
// stuck at 40-75us with 2-barrier phase lockstep per chunk).

__global__ __launch_bounds__(256, 2) void mlp1(
    const unsigned short* __restrict__ featb, const unsigned short* __restrict__ agg,
    const unsigned short* __restrict__ Wt1s, const unsigned short* __restrict__ Wt1n,
    const float* __restrict__ b1, unsigned short* __restrict__ x1b) {
    __shared__ __align__(16) unsigned short w1t[32768];   // 64KB, swizzled
    int wid = threadIdx.x >> 6, lane = threadIdx.x & 63;
    int l15 = lane & 15, quad = lane >> 4;

    // stage W1 -> LDS with 16B-slot swizzle (verified in v5)
    {
        const uint4* gs = reinterpret_cast<const uint4*>(Wt1s);
        const uint4* gn = reinterpret_cast<const uint4*>(Wt1n);
        uint4* ls = reinterpret_cast<uint4*>(w1t);
        uint4* ln = reinterpret_cast<uint4*>(w1t) + 2048;
#pragma unroll
        for (int i = 0; i < 8; ++i) {
            int g = threadIdx.x + i * 256;
            int sw = (g & ~15) | ((g & 15) ^ ((g >> 4) & 7));
            ls[sw] = gs[g];
            ln[sw] = gn[g];
        }
    }
    float bv1[2];
    bv1[0] = b1[wid * 32 + l15];
    bv1[1] = b1[wid * 32 + 16 + l15];

    auto loadA = [&](int cc, bf16x8 (&Afd)[2][4], bf16x8 (&Aad)[2][4]) {
#pragma unroll
        for (int rg = 0; rg < 2; ++rg) {
            int r = cc * 32 + rg * 16 + l15;  // MCHUNKS*32 == NODES: never OOB
            const unsigned short* fp = featb + (size_t)r * 128 + quad * 8;
            const unsigned short* ap = agg + (size_t)r * 128 + quad * 8;
#pragma unroll
            for (int k = 0; k < 4; ++k) {
                Afd[rg][k] = *reinterpret_cast<const bf16x8*>(fp + k * 32);
                Aad[rg][k] = *reinterpret_cast<const bf16x8*>(ap + k * 32);
            }
        }
    };

    bf16x8 Af[2][4], Aa[2][4];
    int c = blockIdx.x;
    if (c < MCHUNKS) loadA(c, Af, Aa);
    __syncthreads();  // W1 staged

    int swz = l15 & 7;
    const unsigned short* wb0 = w1t + (size_t)(wid * 32 + l15) * 128;
    const unsigned short* wb1 = w1t + (size_t)(wid * 32 + 16 + l15) * 128;

    for (; c < MCHUNKS; c += MLP1GRID) {
        int rbase = c * 32;
        int cn = c + MLP1GRID;

        f32x4 acc[2][2];
#pragma unroll
        for (int rg = 0; rg < 2; ++rg)
#pragma unroll
            for (int nt = 0; nt < 2; ++nt) acc[rg][nt] = {0.f, 0.f, 0.f, 0.f};
#pragma unroll
        for (int k = 0; k < 4; ++k) {
            int so = ((k * 4 + quad) ^ swz) << 3;
            bf16x8 b1s0 = *reinterpret_cast<const bf16x8*>(wb0 + so);
            bf16x8 b1n0 = *reinterpret_cast<const bf16x8*>(wb0 + 16384 + so);
            bf16x8 b1s1 = *reinterpret_cast<const bf16x8*>(wb1 + so);
            bf16x8 b1n1 = *reinterpret_cast<const bf16x8*>(wb1 + 16384 + so);
#pragma unroll
            for (int rg = 0; rg < 2; ++rg) {
                acc[rg][0] = __builtin_amdgcn_mfma_f32_16x16x32_bf16(Af[rg][k], b1s0, acc[rg][0], 0, 0, 0);
                acc[rg][0] = __builtin_amdgcn_mfma_f32_16x16x32_bf16(Aa[rg][k], b1n0, acc[rg][0], 0, 0, 0);
                acc[rg][1] = __builtin_amdgcn_mfma_f32_16x16x32_bf16(Af[rg][k], b1s1, acc[rg][1], 0, 0, 0);
                acc[rg][1] = __builtin_amdgcn_mfma_f32_16x16x32_bf16(Aa[rg][k], b1n1, acc[rg][1], 0, 0, 0);
            }
        }

        // prefetch next chunk's A (overlaps epilogue stores)
        bf16x8 Pf[2][4], Pa[2][4];
        if (cn < MCHUNKS) loadA(cn, Pf, Pa);

        // epilogue: relu+bias -> bf16 -> global x1 (row-major)
#pragma unroll
        for (int nt = 0; nt < 2; ++nt)
#pragma unroll
            for (int rg = 0; rg < 2; ++rg)
#pragma unroll
                for (int rr = 0; rr < 4; ++rr) {
                    float v = fmaxf(acc[rg][nt][rr] + bv1[nt], 0.f);
                    int row = rbase + rg * 16 + quad * 4 + rr;
                    x1b[(size_t)row * 128 + wid * 32 + nt * 16 + l15] = f2b(v);
                }

        if (cn < MCHUNKS) {
#pragma unroll
            for (int rg = 0; rg < 2; ++rg)
#pragma unroll
                for (int k = 0; k < 4; ++k) {
                    Af[rg][k] = Pf[rg][k];
                    Aa[rg][k] = Pa[rg][k];
                }
        }
    }
}

// ---------------- MLP layer 2: barrier-free, B2 in registers ----
// outp = x1@W2s + b2 ; x1h8 = fp8(x1@W2n). x1 rows are L3-hot.

__global__ __launch_bounds__(256, 3) void mlp2(
    const unsigned short* __restrict__ x1b,
    const unsigned short* __restrict__ Wt2s, const unsigned short* __restrict__ Wt2n,
    const float* __restrict__ b2,
    unsigned char* __restrict__ x1h8, float* __restrict__ outp) {
    int wid = threadIdx.x >> 6, lane = threadIdx.x & 63;
    int l15 = lane & 15, quad = lane >> 4;
    int col2 = wid * 16 + l15;

    bf16x8 B2s[4], B2n[4];
#pragma unroll
    for (int k = 0; k < 4; ++k) {
        B2s[k] = gl16(Wt2s + (size_t)col2 * 128 + k * 32 + quad * 8);
        B2n[k] = gl16(Wt2n + (size_t)col2 * 128 + k * 32 + quad * 8);
    }
    float bv2 = b2[col2];
    asm volatile("s_waitcnt vmcnt(0)" ::: "memory");
    __builtin_amdgcn_sched_barrier(0);

    auto loadA = [&](int cc, bf16x8 (&Ad)[2][4]) {
#pragma unroll
        for (int rg = 0; rg < 2; ++rg) {
            int r = cc * 32 + rg * 16 + l15;
            const unsigned short* xp = x1b + (size_t)r * 128 + quad * 8;
#pragma unroll
            for (int k = 0; k < 4; ++k) Ad[rg][k] = *reinterpret_cast<const bf16x8*>(xp + k * 32);
        }
    };

    bf16x8 A[2][4];
    int c = blockIdx.x;
    if (c < MCHUNKS) loadA(c, A);

    for (; c < MCHUNKS; c += MLP2GRID) {
        int rbase = c * 32;
        int cn = c + MLP2GRID;

        f32x4 acc2s[2], acc2n[2];
#pragma unroll
        for (int rg = 0; rg < 2; ++rg) { acc2s[rg] = {0.f, 0.f, 0.f, 0.f}; acc2n[rg] = {0.f, 0.f, 0.f, 0.f}; }
#pragma unroll
        for (int k = 0; k < 4; ++k)
#pragma unroll
            for (int rg = 0; rg < 2; ++rg) {
                acc2s[rg] = __builtin_amdgcn_mfma_f32_16x16x32_bf16(A[rg][k], B2s[k], acc2s[rg], 0, 0, 0);
                acc2n[rg] = __builtin_amdgcn_mfma_f32_16x16x32_bf16(A[rg][k], B2n[k], acc2n[rg], 0, 0, 0);
            }

        bf16x8 P[2][4];
        if (cn < MCHUNKS) loadA(cn, P);

#pragma unroll
        for (int rg = 0; rg < 2; ++rg)
#pragma unroll
            for (int rr = 0; rr < 4; ++rr) {
                int row = rbase + rg * 16 + quad * 4 + rr;
                float vn = acc2n[rg][rr];
                int pk = __builtin_amdgcn_cvt_pk_fp8_f32(vn, vn, 0, false);
                x1h8[(size_t)row * 64 + col2] = (unsigned char)(pk & 0xFF);
                outp[(size_t)row * 64 + col2] = acc2s[rg][rr] + bv2;
            }

        if (cn < MCHUNKS) {
#pragma unroll
            for (int rg = 0; rg < 2; ++rg)
#pragma unroll
                for (int k = 0; k < 4; ++k) A[rg][k] = P[rg][k];
        }
    }
}

// ---------------- launch ----------------

extern "C" void kernel_launch(void* const* d_in, const int* in_sizes, int n_in,
                              void* d_out, int out_size, void* d_ws, size_t ws_size,
                              hipStream_t stream) {
    const float* features = (const float*)d_in[0];
    const int* esrc = (const int*)d_in[1];
    const int* edst = (const int*)d_in[2];
    const float* W1s = (const float*)d_in[3];
    const float* W1n = (const float*)d_in[4];
    const float* b1  = (const float*)d_in[5];
    const float* W2s = (const float*)d_in[6];
    const float* W2n = (const float*)d_in[7];
    const float* b2  = (const float*)d_in[8];
    float* out = (float*)d_out;

    char* ws = (char*)d_ws;
    size_t off = 0;
    auto alloc = [&](size_t bytes) {
        void* p = ws + off;
        off += (bytes + 255) & ~(size_t)255;
        return p;
    };
    int* bucket_cnt = (int*)alloc(512 * 4);
    int* bucket_off = (int*)alloc(512 * 4);
    int* gcursor    = (int*)alloc(512 * 4);
    int* row_ptr    = (int*)alloc((size_t)(NODES + 1) * 4);
    int* src_sorted = (int*)alloc((size_t)EDGES * 4);
    unsigned* pairs = (unsigned*)alloc((size_t)EDGES * 4);
    unsigned short* featb = (unsigned short*)alloc((size_t)NODES * 128 * 2);
    unsigned char*  feat8 = (unsigned char*)alloc((size_t)(NODES + 1) * 128);  // +zero pad row
    unsigned short* agg1  = (unsigned short*)alloc((size_t)NODES * 128 * 2);
    unsigned short* x1b   = (unsigned short*)alloc((size_t)NODES * 128 * 2);   // x1 bf16
    unsigned char*  x1h8  = (unsigned char*)alloc((size_t)(NODES + 1) * 64);   // +zero pad row
    unsigned short* Wt1s  = (unsigned short*)alloc(16384 * 2);
    unsigned short* Wt1n  = (unsigned short*)alloc(16384 * 2);
    unsigned short* Wt2s  = (unsigned short*)alloc(8192 * 2);
    unsigned short* Wt2n  = (unsigned short*)alloc(8192 * 2);

    // zero pad rows + bucket counters
    hipMemsetAsync(bucket_cnt, 0, 512 * 4, stream);
    hipMemsetAsync(feat8 + (size_t)NODES * 128, 0, 128, stream);
    hipMemsetAsync(x1h8 + (size_t)NODES * 64, 0, 64, stream);

    // fused conversions + coarse histogram
    conv_hist<<<CONVB + (EDGES + 16383) / 16384, 256, 0, stream>>>(
        features, featb, feat8, NODES * 128 / 4, W1s, W1n, W2s, W2n,
        Wt1s, Wt1n, Wt2s, Wt2n, edst, bucket_cnt);

    bscan_kernel<<<1, 512, 0, stream>>>(bucket_cnt, bucket_off, gcursor, row_ptr);
    binscat_kernel<<<(EDGES + CHUNK - 1) / CHUNK, 256, 0, stream>>>(esrc, edst, gcursor, pairs);
    localsort_kernel<<<NBUCK, 256, 0, stream>>>(pairs, bucket_off, row_ptr, src_sorted);

    // layer 1 aggregation (fp8 gather -> bf16 agg matrix); 4 nodes/wave
    agg128_fp8<<<(NODES / 4 * 64 + 255) / 256, 256, 0, stream>>>(feat8, row_ptr, src_sorted, agg1);

    // MLP split into two barrier-free streaming GEMMs
    mlp1<<<MLP1GRID, 256, 0, stream>>>(featb, agg1, Wt1s, Wt1n, b1, x1b);
    mlp2<<<MLP2GRID, 256, 0, stream>>>(x1b, Wt2s, Wt2n, b2, x1h8, out);

    // out += mean-neigh(x1h); 8 nodes/wave
    agg64_add8<<<(NODES / 8 * 64 + 255) / 256, 256, 0, stream>>>(x1h8, row_ptr, src_sorted, out);
}

// Round 9
// 237.362 us; speedup vs baseline: 1.1258x; 1.1258x over previous
//
#include <hip/hip_runtime.h>

#define NODES 100000
#define EDGES 1600000
#define BSH 8
#define NBUCK ((NODES + 255) >> BSH)   // 391
#define CHUNK 4096
#define LMAX 8192
#define NCH64 ((NODES + 63) / 64)      // 1563 (1563*64 = 100032, tail clamped)
#define CONVB 12500                    // blocks for conv part of conv_hist
#define MLPGRID 512                    // 2 blocks/CU (LDS = 80 KB exactly)
// IN_F = HID_F = 128, OUT_F = 64

using bf16x8 = __attribute__((ext_vector_type(8))) short;
using f32x4  = __attribute__((ext_vector_type(4))) float;
using f32x2  = __attribute__((ext_vector_type(2))) float;

__device__ __forceinline__ unsigned short f2b(float f) {
    unsigned u = __builtin_bit_cast(unsigned, f);
    unsigned r = (u + 0x7FFFu + ((u >> 16) & 1u)) >> 16;
    return (unsigned short)r;
}

// ---- packed f32 helpers (CDNA VOP3P; dual-pump FP32) ----
__device__ __forceinline__ f32x2 pkadd(f32x2 a, f32x2 b) {
    f32x2 d;
    asm("v_pk_add_f32 %0, %1, %2" : "=v"(d) : "v"(a), "v"(b));
    return d;
}
__device__ __forceinline__ f32x2 pkfma(f32x2 a, f32x2 b, f32x2 c) {
    f32x2 d;
    asm("v_pk_fma_f32 %0, %1, %2, %3" : "=v"(d) : "v"(a), "v"(b), "v"(c));
    return d;
}
__device__ __forceinline__ unsigned cvt2bf(float lo, float hi) {
    unsigned r;
    asm("v_cvt_pk_bf16_f32 %0, %1, %2" : "=v"(r) : "v"(lo), "v"(hi));
    return r;
}

// pinned 16B global load (volatile: cannot be sunk/rematerialized)
__device__ __forceinline__ bf16x8 gl16(const unsigned short* p) {
    bf16x8 r;
    asm volatile("global_load_dwordx4 %0, %1, off" : "=&v"(r) : "v"(p));
    return r;
}

// unpack 8 fp8 (uint2) and accumulate into 4 packed-f32 accumulators
__device__ __forceinline__ void addpk8(f32x2* a, uint2 v) {
    a[0] = pkadd(a[0], __builtin_amdgcn_cvt_pk_f32_fp8((int)v.x, false));
    a[1] = pkadd(a[1], __builtin_amdgcn_cvt_pk_f32_fp8((int)v.x, true));
    a[2] = pkadd(a[2], __builtin_amdgcn_cvt_pk_f32_fp8((int)v.y, false));
    a[3] = pkadd(a[3], __builtin_amdgcn_cvt_pk_f32_fp8((int)v.y, true));
}

// ---------------- fused conversions + coarse histogram ----------------

__global__ __launch_bounds__(256) void conv_hist(
    const float* __restrict__ in, unsigned short* __restrict__ outb,
    unsigned char* __restrict__ outq, int n4,
    const float* __restrict__ W1s, const float* __restrict__ W1n,
    const float* __restrict__ W2s, const float* __restrict__ W2n,
    unsigned short* __restrict__ Wt1s, unsigned short* __restrict__ Wt1n,
    unsigned short* __restrict__ Wt2s, unsigned short* __restrict__ Wt2n,
    const int* __restrict__ dst, int* __restrict__ bucket_cnt) {
    int t = threadIdx.x;
    if (blockIdx.x < CONVB) {
        int i = blockIdx.x * 256 + t;
        if (i < n4) {
            float4 v = reinterpret_cast<const float4*>(in)[i];
            uint2 o;
            o.x = (unsigned)f2b(v.x) | ((unsigned)f2b(v.y) << 16);
            o.y = (unsigned)f2b(v.z) | ((unsigned)f2b(v.w) << 16);
            reinterpret_cast<uint2*>(outb)[i] = o;
            int pk = __builtin_amdgcn_cvt_pk_fp8_f32(v.x, v.y, 0, false);
            pk = __builtin_amdgcn_cvt_pk_fp8_f32(v.z, v.w, pk, true);
            reinterpret_cast<unsigned*>(outq)[i] = (unsigned)pk;
        }
        if (i < 16384) {
            int k = i >> 7, n = i & 127;
            Wt1s[n * 128 + k] = f2b(W1s[i]);
            Wt1n[n * 128 + k] = f2b(W1n[i]);
        }
        if (i < 8192) {
            int k = i >> 6, n = i & 63;
            Wt2s[n * 128 + k] = f2b(W2s[i]);
            Wt2n[n * 128 + k] = f2b(W2n[i]);
        }
        return;
    }
    // ---- bhist part ----
    __shared__ int lcnt[512];
    lcnt[t] = 0; lcnt[t + 256] = 0;
    __syncthreads();
    int base = (blockIdx.x - CONVB) * 16384;
    int n = EDGES - base;
    if (n > 16384) n = 16384;
    const int4* d4 = reinterpret_cast<const int4*>(dst + base);
    for (int i = t; i < (n >> 2); i += 256) {
        int4 d = d4[i];
        atomicAdd(&lcnt[d.x >> BSH], 1);
        atomicAdd(&lcnt[d.y >> BSH], 1);
        atomicAdd(&lcnt[d.z >> BSH], 1);
        atomicAdd(&lcnt[d.w >> BSH], 1);
    }
    for (int i = (n & ~3) + t; i < n; i += 256) atomicAdd(&lcnt[dst[base + i] >> BSH], 1);
    __syncthreads();
    if (lcnt[t]) atomicAdd(&bucket_cnt[t], lcnt[t]);
    if (lcnt[t + 256]) atomicAdd(&bucket_cnt[t + 256], lcnt[t + 256]);
}

__global__ void bscan_kernel(const int* __restrict__ bucket_cnt, int* __restrict__ bucket_off,
                             int* __restrict__ gcursor, int* __restrict__ row_ptr) {
    __shared__ int sh[512];
    int t = threadIdx.x;
    int v = (t < NBUCK) ? bucket_cnt[t] : 0;
    sh[t] = v;
    __syncthreads();
    for (int off = 1; off < 512; off <<= 1) {
        int x = (t >= off) ? sh[t - off] : 0;
        __syncthreads();
        sh[t] += x;
        __syncthreads();
    }
    int excl = sh[t] - v;
    if (t < NBUCK) { bucket_off[t] = excl; gcursor[t] = excl; }
    if (t == NBUCK) bucket_off[t] = EDGES;
    if (t == 0) row_ptr[NODES] = EDGES;
}

// Bin edges by coarse bucket; write packed (dst&255)<<24|src runs.
__global__ __launch_bounds__(256) void binscat_kernel(
    const int* __restrict__ src, const int* __restrict__ dst,
    int* __restrict__ gcursor, unsigned* __restrict__ pairs) {
    __shared__ int cnt[512];
    __shared__ int scn[512];
    __shared__ int gbs[512];
    __shared__ int cur[512];
    __shared__ uint2 stage[CHUNK];
    int t = threadIdx.x;
    int base = blockIdx.x * CHUNK;
    int n = EDGES - base;
    if (n > CHUNK) n = CHUNK;

    cnt[t] = 0; cnt[t + 256] = 0;
    __syncthreads();

    uint2 my[16];
#pragma unroll
    for (int i = 0; i < 16; ++i) {
        int idx = t + i * 256;
        if (idx < n) {
            int d = dst[base + idx];
            int s = src[base + idx];
            my[i] = make_uint2((unsigned)d, (unsigned)s);
            atomicAdd(&cnt[d >> BSH], 1);
        } else {
            my[i] = make_uint2(0xFFFFFFFFu, 0);
        }
    }
    __syncthreads();
    scn[t] = cnt[t]; scn[t + 256] = cnt[t + 256];
    __syncthreads();
    for (int off = 1; off < 512; off <<= 1) {
        int a0 = (t >= off) ? scn[t - off] : 0;
        int a1 = (t + 256 >= off) ? scn[t + 256 - off] : 0;
        __syncthreads();
        scn[t] += a0; scn[t + 256] += a1;
        __syncthreads();
    }
    cur[t] = scn[t] - cnt[t];
    cur[t + 256] = scn[t + 256] - cnt[t + 256];
    __syncthreads();
#pragma unroll
    for (int i = 0; i < 16; ++i) {
        if (my[i].x != 0xFFFFFFFFu) {
            int b = (int)(my[i].x >> BSH);
            int p = atomicAdd(&cur[b], 1);
            stage[p] = my[i];
        }
    }
    for (int b2 = t; b2 < 512; b2 += 256) {
        int c = cnt[b2];
        gbs[b2] = (c > 0 && b2 < NBUCK) ? atomicAdd(&gcursor[b2], c) : 0;
    }
    __syncthreads();
    for (int idx = t; idx < n; idx += 256) {
        uint2 p = stage[idx];
        int b = (int)(p.x >> BSH);
        int excl = scn[b] - cnt[b];
        pairs[gbs[b] + idx - excl] = ((p.x & 255u) << 24) | p.y;
    }
}

__global__ __launch_bounds__(256) void localsort_kernel(
    const unsigned* __restrict__ pairs, const int* __restrict__ bucket_off,
    int* __restrict__ row_ptr, int* __restrict__ src_sorted) {
    __shared__ int cnt[256];
    __shared__ int cur[256];
    __shared__ int stage[LMAX];
    int b = blockIdx.x;
    int t = threadIdx.x;
    int node0 = b << BSH;
    int pbeg = bucket_off[b], pend = bucket_off[b + 1];
    int n = pend - pbeg;
    cnt[t] = 0;
    __syncthreads();
    for (int e = pbeg + t; e < pend; e += 256)
        atomicAdd(&cnt[(int)(pairs[e] >> 24)], 1);
    __syncthreads();
    int v = cnt[t];
    cur[t] = v;
    __syncthreads();
    for (int off = 1; off < 256; off <<= 1) {
        int x = (t >= off) ? cur[t - off] : 0;
        __syncthreads();
        cur[t] += x;
        __syncthreads();
    }
    int excl = cur[t] - v;
    int node = node0 + t;
    if (node < NODES) row_ptr[node] = pbeg + excl;
    cur[t] = excl;
    __syncthreads();
    if (n <= LMAX) {
        for (int e = pbeg + t; e < pend; e += 256) {
            unsigned p = pairs[e];
            int pos = atomicAdd(&cur[(int)(p >> 24)], 1);
            stage[pos] = (int)(p & 0xFFFFFFu);
        }
        __syncthreads();
        for (int i = t; i < n; i += 256) src_sorted[pbeg + i] = stage[i];
    } else {
        for (int e = pbeg + t; e < pend; e += 256) {
            unsigned p = pairs[e];
            int pos = atomicAdd(&cur[(int)(p >> 24)], 1);
            src_sorted[pbeg + pos] = (int)(p & 0xFFFFFFu);
        }
    }
}

// ---------------- Mean aggregation, fp8 gather ----------------

__global__ __launch_bounds__(256) void agg128_fp8(
    const unsigned char* __restrict__ xq, const int* __restrict__ row_ptr,
    const int* __restrict__ srcs, unsigned short* __restrict__ out) {
    int wave = (blockIdx.x * 256 + threadIdx.x) >> 6;
    int lane = threadIdx.x & 63;
    int sl = lane & 15;
    int n = wave * 4 + (lane >> 4);
    if (n >= NODES) return;
    int beg = row_ptr[n], end = row_ptr[n + 1];
    int gb = lane & 48;  // group base lane (g*16)

    f32x2 A0[4], A1[4];
#pragma unroll
    for (int i = 0; i < 4; ++i) { A0[i] = {0.f, 0.f}; A1[i] = {0.f, 0.f}; }

    const unsigned char* xs = xq + sl * 8;
    for (int base = beg; base < end; base += 16) {
        int idx = base + sl;
        int sv = (idx < end) ? srcs[idx] : NODES;  // NODES = zero pad row
        uint2 vv[8], ww[8];
#pragma unroll
        for (int j = 0; j < 8; ++j) {
            int s = __shfl(sv, gb + j, 64);
            vv[j] = *reinterpret_cast<const uint2*>(xs + (size_t)s * 128);
        }
#pragma unroll
        for (int j = 0; j < 8; ++j) {
            int s = __shfl(sv, gb + 8 + j, 64);
            ww[j] = *reinterpret_cast<const uint2*>(xs + (size_t)s * 128);
        }
#pragma unroll
        for (int j = 0; j < 8; ++j) addpk8((j & 1) ? A1 : A0, vv[j]);
#pragma unroll
        for (int j = 0; j < 8; ++j) addpk8((j & 1) ? A0 : A1, ww[j]);
    }

    float inv = 1.0f / fmaxf((float)(end - beg), 1.0f);
    f32x2 iv = {inv, inv};
    f32x2 z = {0.f, 0.f};
    f32x2 r0 = pkfma(pkadd(A0[0], A1[0]), iv, z);
    f32x2 r1 = pkfma(pkadd(A0[1], A1[1]), iv, z);
    f32x2 r2 = pkfma(pkadd(A0[2], A1[2]), iv, z);
    f32x2 r3 = pkfma(pkadd(A0[3], A1[3]), iv, z);
    uint4 o;
    o.x = cvt2bf(r0[0], r0[1]);
    o.y = cvt2bf(r1[0], r1[1]);
    o.z = cvt2bf(r2[0], r2[1]);
    o.w = cvt2bf(r3[0], r3[1]);
    *reinterpret_cast<uint4*>(out + (size_t)n * 128 + sl * 8) = o;
}

// agg64: group-per-node, 8-lane groups; v2: 16-edge pipeline (two 8-wide
// srcs loads, 16 gathers in flight — mirrors agg128's proven R3 win).
__global__ __launch_bounds__(256) void agg64_add8(
    const unsigned char* __restrict__ xq, const int* __restrict__ row_ptr,
    const int* __restrict__ srcs, float* __restrict__ out) {
    int wave = (blockIdx.x * 256 + threadIdx.x) >> 6;
    int lane = threadIdx.x & 63;
    int sl = lane & 7;
    int n = wave * 8 + (lane >> 3);
    if (n >= NODES) return;
    int beg = row_ptr[n], end = row_ptr[n + 1];
    int gb = lane & 56;  // group base lane (g*8)

    f32x2 A0[4], A1[4];
#pragma unroll
    for (int i = 0; i < 4; ++i) { A0[i] = {0.f, 0.f}; A1[i] = {0.f, 0.f}; }

    const unsigned char* xs = xq + sl * 8;
    for (int base = beg; base < end; base += 16) {
        int i0 = base + sl, i1 = base + 8 + sl;
        int sv0 = (i0 < end) ? srcs[i0] : NODES;  // zero pad row
        int sv1 = (i1 < end) ? srcs[i1] : NODES;
        uint2 vv[16];
#pragma unroll
        for (int j = 0; j < 8; ++j) {
            int s = __shfl(sv0, gb + j, 64);
            vv[j] = *reinterpret_cast<const uint2*>(xs + (size_t)s * 64);
        }
#pragma unroll
        for (int j = 0; j < 8; ++j) {
            int s = __shfl(sv1, gb + j, 64);
            vv[8 + j] = *reinterpret_cast<const uint2*>(xs + (size_t)s * 64);
        }
#pragma unroll
        for (int j = 0; j < 16; ++j) addpk8((j & 1) ? A1 : A0, vv[j]);
    }

    float inv = 1.0f / fmaxf((float)(end - beg), 1.0f);
    f32x2 iv = {inv, inv};
    float* op = out + (size_t)n * 64 + sl * 8;
    f32x2 r0 = *reinterpret_cast<f32x2*>(op);
    f32x2 r1 = *reinterpret_cast<f32x2*>(op + 2);
    f32x2 r2 = *reinterpret_cast<f32x2*>(op + 4);
    f32x2 r3 = *reinterpret_cast<f32x2*>(op + 6);
    r0 = pkfma(pkadd(A0[0], A1[0]), iv, r0);
    r1 = pkfma(pkadd(A0[1], A1[1]), iv, r1);
    r2 = pkfma(pkadd(A0[2], A1[2]), iv, r2);
    r3 = pkfma(pkadd(A0[3], A1[3]), iv, r3);
    *reinterpret_cast<f32x2*>(op) = r0;
    *reinterpret_cast<f32x2*>(op + 2) = r1;
    *reinterpret_cast<f32x2*>(op + 4) = r2;
    *reinterpret_cast<f32x2*>(op + 6) = r3;
}

// ---------------- Fused MLP v6: 64-row chunks, wave-disjoint A ----
// v5 flaw: all 4 waves loaded the SAME 32 A-rows (4x redundant L2 requests)
// and 3125 chunks fixed the barrier-drain count. v6: chunk = 64 rows; each
// wave owns a disjoint 16-row slice in phase 1 (vs all 128 W1 cols from
// LDS) and a disjoint 16-col slice in phase 2 (vs all 64 rows from x1t).
// Chunks halve (1563), A redundancy -> 0. x1t is [64][128] with XOR slot
// swizzle (slot ^= row&7) instead of padding: LDS = 64K + 16K = 80 KB
// exactly -> still 2 blocks/CU. W1-LDS staging + B2 asm-pin from v5.

__global__ __launch_bounds__(256, 2) void fused_mlp(
    const unsigned short* __restrict__ featb, const unsigned short* __restrict__ agg,
    const unsigned short* __restrict__ Wt1s, const unsigned short* __restrict__ Wt1n,
    const float* __restrict__ b1, const unsigned short* __restrict__ Wt2s,
    const unsigned short* __restrict__ Wt2n, const float* __restrict__ b2,
    unsigned char* __restrict__ x1h8, float* __restrict__ outp) {
    __shared__ __align__(16) unsigned short w1t[32768];    // 64 KB, swizzled
    __shared__ __align__(16) unsigned short x1t[64 * 128]; // 16 KB, swizzled
    int wid = threadIdx.x >> 6, lane = threadIdx.x & 63;
    int l15 = lane & 15, quad = lane >> 4;

    // stage W1 -> LDS with 16B-slot swizzle (proven in v5)
    {
        const uint4* gs = reinterpret_cast<const uint4*>(Wt1s);
        const uint4* gn = reinterpret_cast<const uint4*>(Wt1n);
        uint4* ls = reinterpret_cast<uint4*>(w1t);
        uint4* ln = ls + 2048;
#pragma unroll
        for (int i = 0; i < 8; ++i) {
            int g = threadIdx.x + i * 256;
            int sw = (g & ~15) | ((g & 15) ^ ((g >> 4) & 7));
            ls[sw] = gs[g];
            ln[sw] = gn[g];
        }
    }

    // B2 strips pinned in registers (8 frags, volatile asm)
    int col2 = wid * 16 + l15;
    bf16x8 B2s[4], B2n[4];
#pragma unroll
    for (int k = 0; k < 4; ++k) {
        B2s[k] = gl16(Wt2s + (size_t)col2 * 128 + k * 32 + quad * 8);
        B2n[k] = gl16(Wt2n + (size_t)col2 * 128 + k * 32 + quad * 8);
    }
    float bv2 = b2[col2];
    float bv1[8];
#pragma unroll
    for (int nt = 0; nt < 8; ++nt) bv1[nt] = b1[nt * 16 + l15];

    // per-wave disjoint 16-row A slice
    auto loadA = [&](int cc, bf16x8 (&Afd)[4], bf16x8 (&Aad)[4]) {
        int r = cc * 64 + wid * 16 + l15;
        if (r >= NODES) r = NODES - 1;  // tail clamp (stores guarded)
        const unsigned short* fp = featb + (size_t)r * 128 + quad * 8;
        const unsigned short* ap = agg + (size_t)r * 128 + quad * 8;
#pragma unroll
        for (int k = 0; k < 4; ++k) {
            Afd[k] = *reinterpret_cast<const bf16x8*>(fp + k * 32);
            Aad[k] = *reinterpret_cast<const bf16x8*>(ap + k * 32);
        }
    };

    bf16x8 Af[4], Aa[4];
    int c = blockIdx.x;
    if (c < NCH64) loadA(c, Af, Aa);

    // drain pinned B2 loads; fence; W1 visible (rule #18 ordering)
    asm volatile("s_waitcnt vmcnt(0)" ::: "memory");
    __builtin_amdgcn_sched_barrier(0);
    __syncthreads();

    int swz = l15 & 7;  // W1 read swizzle key (col&7 = l15&7)

    for (; c < NCH64; c += MLPGRID) {
        int rbase = c * 64;
        int cn = c + MLPGRID;

        // ---- phase 1: my 16 rows x all 128 W1 cols ----
        f32x4 acc[8];
#pragma unroll
        for (int nt = 0; nt < 8; ++nt) acc[nt] = {0.f, 0.f, 0.f, 0.f};
#pragma unroll
        for (int k = 0; k < 4; ++k) {
            int so = ((k * 4 + quad) ^ swz) << 3;  // swizzled 16B slot, in shorts
#pragma unroll
            for (int nt = 0; nt < 8; ++nt) {
                const unsigned short* wb = w1t + (size_t)(nt * 16 + l15) * 128;
                bf16x8 b1s = *reinterpret_cast<const bf16x8*>(wb + so);
                bf16x8 b1n = *reinterpret_cast<const bf16x8*>(wb + 16384 + so);
                acc[nt] = __builtin_amdgcn_mfma_f32_16x16x32_bf16(Af[k], b1s, acc[nt], 0, 0, 0);
                acc[nt] = __builtin_amdgcn_mfma_f32_16x16x32_bf16(Aa[k], b1n, acc[nt], 0, 0, 0);
            }
        }

        // prefetch next chunk's A (overlaps epilogue + phase 2)
        bf16x8 Pf[4], Pa[4];
        if (cn < NCH64) loadA(cn, Pf, Pa);

        // ---- epilogue: relu+bias -> x1t (XOR slot swizzle) ----
        // C layout: col = nt*16+l15, row(in-tile) = quad*4+rr
#pragma unroll
        for (int nt = 0; nt < 8; ++nt)
#pragma unroll
            for (int rr = 0; rr < 4; ++rr) {
                float v = fmaxf(acc[nt][rr] + bv1[nt], 0.f);
                int row = wid * 16 + quad * 4 + rr;        // 0..63
                int col = nt * 16 + l15;                   // 0..127
                int slot = (col >> 3) ^ (row & 7);         // XOR low 3 bits
                x1t[row * 128 + slot * 8 + (col & 7)] = f2b(v);
            }
        __syncthreads();

        // ---- phase 2: my 16 cols x all 64 rows ----
        f32x4 a2s[4], a2n[4];
#pragma unroll
        for (int mt = 0; mt < 4; ++mt) { a2s[mt] = {0.f, 0.f, 0.f, 0.f}; a2n[mt] = {0.f, 0.f, 0.f, 0.f}; }
#pragma unroll
        for (int k = 0; k < 4; ++k)
#pragma unroll
            for (int mt = 0; mt < 4; ++mt) {
                int row = mt * 16 + l15;
                int slot = (k * 4 + quad) ^ (row & 7);
                bf16x8 a = *reinterpret_cast<const bf16x8*>(x1t + row * 128 + slot * 8);
                a2s[mt] = __builtin_amdgcn_mfma_f32_16x16x32_bf16(a, B2s[k], a2s[mt], 0, 0, 0);
                a2n[mt] = __builtin_amdgcn_mfma_f32_16x16x32_bf16(a, B2n[k], a2n[mt], 0, 0, 0);
            }
        __syncthreads();  // x1t consumed; next iteration may overwrite

        // ---- stores ----
#pragma unroll
        for (int mt = 0; mt < 4; ++mt)
#pragma unroll
            for (int rr = 0; rr < 4; ++rr) {
                int row = rbase + mt * 16 + quad * 4 + rr;
                if (row < NODES) {
                    float vn = a2n[mt][rr];
                    int pk = __builtin_amdgcn_cvt_pk_fp8_f32(vn, vn, 0, false);
                    x1h8[(size_t)row * 64 + col2] = (unsigned char)(pk & 0xFF);
                    outp[(size_t)row * 64 + col2] = a2s[mt][rr] + bv2;
                }
            }

        if (cn < NCH64) {
#pragma unroll
            for (int k = 0; k < 4; ++k) {
                Af[k] = Pf[k];
                Aa[k] = Pa[k];
            }
        }
    }
}

// ---------------- launch ----------------

extern "C" void kernel_launch(void* const* d_in, const int* in_sizes, int n_in,
                              void* d_out, int out_size, void* d_ws, size_t ws_size,
                              hipStream_t stream) {
    const float* features = (const float*)d_in[0];
    const int* esrc = (const int*)d_in[1];
    const int* edst = (const int*)d_in[2];
    const float* W1s = (const float*)d_in[3];
    const float* W1n = (const float*)d_in[4];
    const float* b1  = (const float*)d_in[5];
    const float* W2s = (const float*)d_in[6];
    const float* W2n = (const float*)d_in[7];
    const float* b2  = (const float*)d_in[8];
    float* out = (float*)d_out;

    char* ws = (char*)d_ws;
    size_t off = 0;
    auto alloc = [&](size_t bytes) {
        void* p = ws + off;
        off += (bytes + 255) & ~(size_t)255;
        return p;
    };
    int* bucket_cnt = (int*)alloc(512 * 4);
    int* bucket_off = (int*)alloc(512 * 4);
    int* gcursor    = (int*)alloc(512 * 4);
    int* row_ptr    = (int*)alloc((size_t)(NODES + 1) * 4);
    int* src_sorted = (int*)alloc((size_t)EDGES * 4);
    unsigned* pairs = (unsigned*)alloc((size_t)EDGES * 4);
    unsigned short* featb = (unsigned short*)alloc((size_t)NODES * 128 * 2);
    unsigned char*  feat8 = (unsigned char*)alloc((size_t)(NODES + 1) * 128);  // +zero pad row
    unsigned short* agg1  = (unsigned short*)alloc((size_t)NODES * 128 * 2);
    unsigned char*  x1h8  = (unsigned char*)alloc((size_t)(NODES + 1) * 64);   // +zero pad row
    unsigned short* Wt1s  = (unsigned short*)alloc(16384 * 2);
    unsigned short* Wt1n  = (unsigned short*)alloc(16384 * 2);
    unsigned short* Wt2s  = (unsigned short*)alloc(8192 * 2);
    unsigned short* Wt2n  = (unsigned short*)alloc(8192 * 2);

    // zero pad rows + bucket counters
    hipMemsetAsync(bucket_cnt, 0, 512 * 4, stream);
    hipMemsetAsync(feat8 + (size_t)NODES * 128, 0, 128, stream);
    hipMemsetAsync(x1h8 + (size_t)NODES * 64, 0, 64, stream);

    // fused conversions + coarse histogram
    conv_hist<<<CONVB + (EDGES + 16383) / 16384, 256, 0, stream>>>(
        features, featb, feat8, NODES * 128 / 4, W1s, W1n, W2s, W2n,
        Wt1s, Wt1n, Wt2s, Wt2n, edst, bucket_cnt);

    bscan_kernel<<<1, 512, 0, stream>>>(bucket_cnt, bucket_off, gcursor, row_ptr);
    binscat_kernel<<<(EDGES + CHUNK - 1) / CHUNK, 256, 0, stream>>>(esrc, edst, gcursor, pairs);
    localsort_kernel<<<NBUCK, 256, 0, stream>>>(pairs, bucket_off, row_ptr, src_sorted);

    // layer 1 aggregation (fp8 gather -> bf16 agg matrix); 4 nodes/wave
    agg128_fp8<<<(NODES / 4 * 64 + 255) / 256, 256, 0, stream>>>(feat8, row_ptr, src_sorted, agg1);

    // fused MLP v6: 64-row chunks, wave-disjoint A, W1 in LDS
    fused_mlp<<<MLPGRID, 256, 0, stream>>>(featb, agg1, Wt1s, Wt1n, b1, Wt2s, Wt2n, b2, x1h8, out);

    // out += mean-neigh(x1h); 8 nodes/wave, 16-deep
    agg64_add8<<<(NODES / 8 * 64 + 255) / 256, 256, 0, stream>>>(x1h8, row_ptr, src_sorted, out);
}